// Round 4
// baseline (132.324 us; speedup 1.0000x reference)
//
#include <hip/hip_runtime.h>

#define BATCH 8
#define NPTS  1024
#define FH    256
#define FW    256
#define FC    256
#define HID   512
#define PADN  1056          // 16-row halo each side (rate <= 9)
#define HALO  16

typedef __attribute__((ext_vector_type(8))) short short8;
typedef __attribute__((ext_vector_type(16))) float f32x16;
typedef unsigned short ushort_t;
typedef unsigned int uint_t;

__device__ __forceinline__ ushort_t f2bf(float f) {
    uint_t u = __builtin_bit_cast(uint_t, f);
    u += 0x7fffu + ((u >> 16) & 1u);          // round-to-nearest-even
    return (ushort_t)(u >> 16);
}
__device__ __forceinline__ float bf2f(ushort_t s) {
    uint_t u = ((uint_t)s) << 16;
    return __builtin_bit_cast(float, u);
}

#define GLOAD16(g, l)                                                     \
    __builtin_amdgcn_global_load_lds(                                     \
        (const __attribute__((address_space(1))) void*)(g),               \
        (__attribute__((address_space(3))) void*)(l), 16, 0, 0)

// ---------------------------------------------------------------------------
// Fused prep kernel: [0,1280) halo zeroing, [1280,2336) weight transpose,
// [2336,4384) bilinear sampling (4 vertices per block).
// ---------------------------------------------------------------------------
__global__ __launch_bounds__(256) void prep_kernel(
    const float* __restrict__ vertices, const float* __restrict__ features,
    const float* __restrict__ w0, const float* __restrict__ w1,
    const float* __restrict__ w2, const float* __restrict__ w3,
    const float* __restrict__ w4, const float* __restrict__ w5,
    ushort_t* __restrict__ wt0, ushort_t* __restrict__ wt1,
    ushort_t* __restrict__ wt2, ushort_t* __restrict__ wt3,
    ushort_t* __restrict__ wt4, ushort_t* __restrict__ wt5,
    ushort_t* __restrict__ XpA, ushort_t* __restrict__ XpB,
    ushort_t* __restrict__ XpC)
{
    __shared__ float tile[64][65];
    const int blk = blockIdx.x;
    const int tid = threadIdx.x;

    if (blk < 1280) {
        // ---- halo zeroing ----
        int i = blk * 256 + tid;
        if (i < 65536) {                   // A halos: 8 * 2 strips * 16*256
            int b = i >> 13, rem = i & 8191;
            int strip = rem >> 12, off = rem & 4095;
            XpA[(size_t)b * (PADN * FC) + (strip ? (PADN - HALO) * FC : 0) + off] = 0;
        }
        int jB = i - 65536;                // B,C halos: 8 * 2 strips * 16*512
        if (jB >= 0 && jB < 262144) {
            ushort_t* T = (jB < 131072) ? XpB : XpC;
            int j = jB & 131071;
            int b = j >> 14, rem = j & 16383;
            int strip = rem >> 13, off = rem & 8191;
            T[(size_t)b * (PADN * HID) + (strip ? (PADN - HALO) * HID : 0) + off] = 0;
        }
        return;
    }

    if (blk < 2336) {
        // ---- weight transpose: w [3][CIN][512] fp32 -> wt [512][3*CIN] bf16 ----
        int j = blk - 1280;
        const float* w; ushort_t* wt; int CIN, kk0, co0;
        if (j < 96) {
            w = w0; wt = wt0; CIN = FC;
            kk0 = (j % 12) * 64; co0 = (j / 12) * 64;
        } else {
            int j2 = j - 96;
            int layer = j2 / 192, jj = j2 % 192;
            const float* ws[5]  = {w1, w2, w3, w4, w5};
            ushort_t*   wts[5]  = {wt1, wt2, wt3, wt4, wt5};
            w = ws[layer]; wt = wts[layer]; CIN = HID;
            kk0 = (jj % 24) * 64; co0 = (jj / 24) * 64;
        }
        int tap = kk0 / CIN, ci0 = kk0 - tap * CIN;
        int K3 = 3 * CIN;
#pragma unroll 4
        for (int it = 0; it < 16; ++it) {
            int r = it * 4 + (tid >> 6);
            tile[r][tid & 63] = w[((size_t)tap * CIN + ci0 + r) * HID + co0 + (tid & 63)];
        }
        __syncthreads();
#pragma unroll 4
        for (int it = 0; it < 16; ++it) {
            int co = it * 4 + (tid >> 6);
            wt[(size_t)(co0 + co) * K3 + kk0 + (tid & 63)] = f2bf(tile[tid & 63][co]);
        }
        return;
    }

    // ---- bilinear sampling: 4 vertices per block ----
    {
        int p = (blk - 2336) * 4 + (tid >> 6);   // b*NPTS + n
        int b = p >> 10;
        int n = p & 1023;
        int t = tid & 63;                        // 4 channels each

        float y = vertices[2 * p + 0];
        float x = vertices[2 * p + 1];
        float y0f = floorf(y), x0f = floorf(x);
        float wy1 = y - y0f, wx1 = x - x0f;
        float wy0 = 1.f - wy1, wx0 = 1.f - wx1;
        int y0 = (int)y0f, x0 = (int)x0f;

        float4 acc = make_float4(0.f, 0.f, 0.f, 0.f);
        const float4* fbase = (const float4*)features + (size_t)b * FH * FW * (FC / 4);

#define CORNER(yi, xi, wgt) {                                                  \
        int yy = (yi), xx = (xi);                                              \
        float wv = ((yy >= 0) && (yy < FH) && (xx >= 0) && (xx < FW)) ? (wgt) : 0.f; \
        int yc = yy < 0 ? 0 : (yy > FH - 1 ? FH - 1 : yy);                     \
        int xc = xx < 0 ? 0 : (xx > FW - 1 ? FW - 1 : xx);                     \
        float4 v = fbase[((size_t)yc * FW + xc) * (FC / 4) + t];               \
        acc.x += v.x * wv; acc.y += v.y * wv; acc.z += v.z * wv; acc.w += v.w * wv; }

        CORNER(y0,     x0,     wy0 * wx0);
        CORNER(y0,     x0 + 1, wy0 * wx1);
        CORNER(y0 + 1, x0,     wy1 * wx0);
        CORNER(y0 + 1, x0 + 1, wy1 * wx1);
#undef CORNER

        ushort4 o;
        o.x = f2bf(acc.x); o.y = f2bf(acc.y); o.z = f2bf(acc.z); o.w = f2bf(acc.w);
        *(ushort4*)(XpA + ((size_t)b * PADN + HALO + n) * FC + 4 * t) = o;
    }
}

// ---------------------------------------------------------------------------
// Dilated conv as MFMA GEMM, tile 128x128 (M x CO), 4 waves (2x2),
// wave tile 64x64 (2x2 frags of 32x32x16). BK=64, double-buffered LDS,
// counted-vmcnt schedule (T3/T4): next tile's 8 gload_lds stay in flight
// across the barrier; s_waitcnt vmcnt(8) guarantees current tile is ready.
// Grid 256 flat, XCD-bijective decode: 4 bn-blocks of one m-panel per XCD.
// ---------------------------------------------------------------------------
template <int CIN>
__global__ __launch_bounds__(256) void conv_mfma(
    const ushort_t* __restrict__ Xp,   // [8][1056][CIN] bf16
    const ushort_t* __restrict__ Wt,   // [512][3*CIN]  bf16
    const float* __restrict__ bias,    // [512] fp32
    ushort_t* __restrict__ Yp,         // [8][1056][512] bf16 (interior write)
    int rate)
{
    constexpr int K3 = 3 * CIN;
    constexpr int NT = K3 / 64;        // K-steps
    __shared__ short lds[2][16384];    // [buf][A(8192) | B(8192)] shorts = 64 KB

    const int tid  = threadIdx.x;
    const int wid  = tid >> 6;
    const int lane = tid & 63;
    const int wm   = wid >> 1, wn = wid & 1;

    const int h   = blockIdx.x;              // 0..255
    const int loc = h >> 3;                  // 0..31
    const int bm  = (h & 7) * 8 + (loc >> 2);// 0..63 (XCD h&7 owns 8 m-panels)
    const int bn  = loc & 3;                 // 0..3
    const int batch = bm >> 3;
    const int n0    = (bm & 7) * 128;
    const int co0   = bn * 128;

    const short* Xbase = (const short*)Xp + ((size_t)batch * PADN + HALO + n0) * CIN;
    const short* Wbase = (const short*)Wt + (size_t)co0 * K3;

    // ---- staging: one K-step = A[128][64] + B[128][64] bf16 tiles ----
    // 8 gload_lds(16B) per wave per tile -> vmcnt quantum = 8.
    auto stage = [&](int buf, int kt) {
        const int tap = (kt << 6) / CIN;
        const int ci0 = (kt << 6) - tap * CIN;
        const short* Ag = Xbase + (ptrdiff_t)(tap - 1) * rate * CIN + ci0;
        const short* Bg = Wbase + (kt << 6);
        short* ldsA = &lds[buf][0];
        short* ldsB = &lds[buf][8192];
#pragma unroll
        for (int it = 0; it < 4; ++it) {
            int row  = wid * 32 + it * 8 + (lane >> 3);
            int chnk = (lane & 7) ^ (row & 7);           // inverse swizzle on src
            GLOAD16(Ag + (size_t)row * CIN + chnk * 8, ldsA + ((wid * 4 + it) << 9));
            GLOAD16(Bg + (size_t)row * K3  + chnk * 8, ldsB + ((wid * 4 + it) << 9));
        }
    };

    // ---- accumulators init with bias ----
    f32x16 acc[2][2];
    const int rowA0 = wm * 64 + (lane & 31);
    const int rowB0 = wn * 64 + (lane & 31);
#pragma unroll
    for (int j = 0; j < 2; ++j) {
        float bv = bias[co0 + wn * 64 + j * 32 + (lane & 31)];
#pragma unroll
        for (int i = 0; i < 2; ++i)
#pragma unroll
            for (int r = 0; r < 16; ++r) acc[i][j][r] = bv;
    }

    stage(0, 0);

    int cur = 0;
    for (int kt = 0; kt < NT; ++kt) {
        if (kt + 1 < NT) {
            stage(cur ^ 1, kt + 1);
            asm volatile("s_waitcnt vmcnt(8)" ::: "memory");  // tile kt ready, next stays in flight
        } else {
            asm volatile("s_waitcnt vmcnt(0)" ::: "memory");
        }
        __builtin_amdgcn_s_barrier();
        __builtin_amdgcn_sched_barrier(0);

        const short* As = &lds[cur][0];
        const short* Bs = &lds[cur][8192];
        __builtin_amdgcn_s_setprio(1);
#pragma unroll
        for (int ks = 0; ks < 4; ++ks) {
            int ch = ks * 2 + (lane >> 5);
            short8 av[2], bv[2];
#pragma unroll
            for (int i = 0; i < 2; ++i) {
                int ra = rowA0 + i * 32;
                av[i] = *(const short8*)(As + ra * 64 + ((ch ^ (ra & 7)) << 3));
            }
#pragma unroll
            for (int j = 0; j < 2; ++j) {
                int rb = rowB0 + j * 32;
                bv[j] = *(const short8*)(Bs + rb * 64 + ((ch ^ (rb & 7)) << 3));
            }
#pragma unroll
            for (int i = 0; i < 2; ++i)
#pragma unroll
                for (int j = 0; j < 2; ++j)
                    acc[i][j] = __builtin_amdgcn_mfma_f32_32x32x16_bf16(
                        av[i], bv[j], acc[i][j], 0, 0, 0);
        }
        __builtin_amdgcn_s_setprio(0);
        __builtin_amdgcn_sched_barrier(0);
        __builtin_amdgcn_s_barrier();
        cur ^= 1;
    }

    // ---- epilogue: ReLU + bf16 store into padded interior ----
    ushort_t* Yb = Yp + ((size_t)batch * PADN + HALO + n0) * HID + co0;
#pragma unroll
    for (int i = 0; i < 2; ++i)
#pragma unroll
        for (int j = 0; j < 2; ++j) {
            int cco = wn * 64 + j * 32 + (lane & 31);
#pragma unroll
            for (int r = 0; r < 16; ++r) {
                int rrow = wm * 64 + i * 32 + (r & 3) + 8 * (r >> 2) + 4 * (lane >> 5);
                float v = acc[i][j][r];
                v = v > 0.f ? v : 0.f;
                Yb[(size_t)rrow * HID + cco] = f2bf(v);
            }
        }
}

// ---------------------------------------------------------------------------
// Offset head: out[p,:] = vertices[p,:] + h[p,:] @ w_off  (bf16 h, fp32 w)
// ---------------------------------------------------------------------------
__global__ __launch_bounds__(64) void head_kernel(
    const ushort_t* __restrict__ h, const float* __restrict__ w_off,
    const float* __restrict__ vertices, float* __restrict__ out)
{
    int p = blockIdx.x;
    int b = p >> 10, n = p & 1023;
    int t = threadIdx.x;
    const ushort_t* hr = h + ((size_t)b * PADN + HALO + n) * HID + t * 8;

    uint4 raw = *(const uint4*)hr;
    ushort_t hv[8];
    hv[0] = raw.x & 0xffff; hv[1] = raw.x >> 16;
    hv[2] = raw.y & 0xffff; hv[3] = raw.y >> 16;
    hv[4] = raw.z & 0xffff; hv[5] = raw.z >> 16;
    hv[6] = raw.w & 0xffff; hv[7] = raw.w >> 16;

    float s0 = 0.f, s1 = 0.f;
#pragma unroll
    for (int k = 0; k < 8; ++k) {
        float x = bf2f(hv[k]);
        s0 += x * w_off[(t * 8 + k) * 2 + 0];
        s1 += x * w_off[(t * 8 + k) * 2 + 1];
    }
#pragma unroll
    for (int off = 32; off >= 1; off >>= 1) {
        s0 += __shfl_down(s0, off);
        s1 += __shfl_down(s1, off);
    }
    if (t == 0) {
        out[2 * p + 0] = vertices[2 * p + 0] + s0;
        out[2 * p + 1] = vertices[2 * p + 1] + s1;
    }
}

// ---------------------------------------------------------------------------
extern "C" void kernel_launch(void* const* d_in, const int* in_sizes, int n_in,
                              void* d_out, int out_size, void* d_ws, size_t ws_size,
                              hipStream_t stream)
{
    (void)in_sizes; (void)n_in; (void)out_size; (void)ws_size;

    const float* vertices = (const float*)d_in[0];
    const float* features = (const float*)d_in[1];
    const float* w[6]  = {(const float*)d_in[2], (const float*)d_in[4],
                          (const float*)d_in[6], (const float*)d_in[8],
                          (const float*)d_in[10], (const float*)d_in[12]};
    const float* bb[6] = {(const float*)d_in[3], (const float*)d_in[5],
                          (const float*)d_in[7], (const float*)d_in[9],
                          (const float*)d_in[11], (const float*)d_in[13]};
    const float* w_off = (const float*)d_in[14];
    float* out = (float*)d_out;

    // ---- workspace layout ----
    char* p = (char*)d_ws;
    ushort_t* wt[6];
    wt[0] = (ushort_t*)p; p += (size_t)HID * (3 * FC) * 2;          // 768 KB
    for (int i = 1; i < 6; ++i) { wt[i] = (ushort_t*)p; p += (size_t)HID * (3 * HID) * 2; }
    ushort_t* XpA = (ushort_t*)p; p += (size_t)BATCH * PADN * FC  * 2;
    ushort_t* XpB = (ushort_t*)p; p += (size_t)BATCH * PADN * HID * 2;
    ushort_t* XpC = (ushort_t*)p;

    // ---- fused prep: halos + weight transpose + sampling ----
    prep_kernel<<<4384, 256, 0, stream>>>(
        vertices, features, w[0], w[1], w[2], w[3], w[4], w[5],
        wt[0], wt[1], wt[2], wt[3], wt[4], wt[5], XpA, XpB, XpC);

    // ---- conv stack (A -> B -> C -> B -> C -> B -> C) ----
    static const int rates[6] = {1, 3, 9, 9, 3, 1};
    conv_mfma<FC><<<256, 256, 0, stream>>>(XpA, wt[0], bb[0], XpB, rates[0]);
    ushort_t* src = XpB;
    ushort_t* dst = XpC;
    for (int i = 1; i < 6; ++i) {
        conv_mfma<HID><<<256, 256, 0, stream>>>(src, wt[i], bb[i], dst, rates[i]);
        ushort_t* tmp = src; src = dst; dst = tmp;
    }

    // ---- head ----
    head_kernel<<<BATCH * NPTS, 64, 0, stream>>>(src, w_off, vertices, out);
}

// Round 5
// 131.287 us; speedup vs baseline: 1.0079x; 1.0079x over previous
//
#include <hip/hip_runtime.h>

#define BATCH 8
#define NPTS  1024
#define FH    256
#define FW    256
#define FC    256
#define HID   512
#define PADN  1056          // 16-row halo each side (rate <= 9)
#define HALO  16

typedef __attribute__((ext_vector_type(8))) short short8;
typedef __attribute__((ext_vector_type(16))) float f32x16;
typedef unsigned short ushort_t;
typedef unsigned int uint_t;

__device__ __forceinline__ ushort_t f2bf(float f) {
    uint_t u = __builtin_bit_cast(uint_t, f);
    u += 0x7fffu + ((u >> 16) & 1u);          // round-to-nearest-even
    return (ushort_t)(u >> 16);
}
__device__ __forceinline__ float bf2f(ushort_t s) {
    uint_t u = ((uint_t)s) << 16;
    return __builtin_bit_cast(float, u);
}

#define GLOAD16(g, l)                                                     \
    __builtin_amdgcn_global_load_lds(                                     \
        (const __attribute__((address_space(1))) void*)(g),               \
        (__attribute__((address_space(3))) void*)(l), 16, 0, 0)

// ---------------------------------------------------------------------------
// Fused prep kernel: [0,1280) halo zeroing, [1280,2336) weight transpose,
// [2336,4384) bilinear sampling (4 vertices per block).
// ---------------------------------------------------------------------------
__global__ __launch_bounds__(256) void prep_kernel(
    const float* __restrict__ vertices, const float* __restrict__ features,
    const float* __restrict__ w0, const float* __restrict__ w1,
    const float* __restrict__ w2, const float* __restrict__ w3,
    const float* __restrict__ w4, const float* __restrict__ w5,
    ushort_t* __restrict__ wt0, ushort_t* __restrict__ wt1,
    ushort_t* __restrict__ wt2, ushort_t* __restrict__ wt3,
    ushort_t* __restrict__ wt4, ushort_t* __restrict__ wt5,
    ushort_t* __restrict__ XpA, ushort_t* __restrict__ XpB,
    ushort_t* __restrict__ XpC)
{
    __shared__ float tile[64][65];
    const int blk = blockIdx.x;
    const int tid = threadIdx.x;

    if (blk < 1280) {
        // ---- halo zeroing ----
        int i = blk * 256 + tid;
        if (i < 65536) {                   // A halos: 8 * 2 strips * 16*256
            int b = i >> 13, rem = i & 8191;
            int strip = rem >> 12, off = rem & 4095;
            XpA[(size_t)b * (PADN * FC) + (strip ? (PADN - HALO) * FC : 0) + off] = 0;
        }
        int jB = i - 65536;                // B,C halos: 8 * 2 strips * 16*512
        if (jB >= 0 && jB < 262144) {
            ushort_t* T = (jB < 131072) ? XpB : XpC;
            int j = jB & 131071;
            int b = j >> 14, rem = j & 16383;
            int strip = rem >> 13, off = rem & 8191;
            T[(size_t)b * (PADN * HID) + (strip ? (PADN - HALO) * HID : 0) + off] = 0;
        }
        return;
    }

    if (blk < 2336) {
        // ---- weight transpose: w [3][CIN][512] fp32 -> wt [512][3*CIN] bf16 ----
        int j = blk - 1280;
        const float* w; ushort_t* wt; int CIN, kk0, co0;
        if (j < 96) {
            w = w0; wt = wt0; CIN = FC;
            kk0 = (j % 12) * 64; co0 = (j / 12) * 64;
        } else {
            int j2 = j - 96;
            int layer = j2 / 192, jj = j2 % 192;
            const float* ws[5]  = {w1, w2, w3, w4, w5};
            ushort_t*   wts[5]  = {wt1, wt2, wt3, wt4, wt5};
            w = ws[layer]; wt = wts[layer]; CIN = HID;
            kk0 = (jj % 24) * 64; co0 = (jj / 24) * 64;
        }
        int tap = kk0 / CIN, ci0 = kk0 - tap * CIN;
        int K3 = 3 * CIN;
#pragma unroll 4
        for (int it = 0; it < 16; ++it) {
            int r = it * 4 + (tid >> 6);
            tile[r][tid & 63] = w[((size_t)tap * CIN + ci0 + r) * HID + co0 + (tid & 63)];
        }
        __syncthreads();
#pragma unroll 4
        for (int it = 0; it < 16; ++it) {
            int co = it * 4 + (tid >> 6);
            wt[(size_t)(co0 + co) * K3 + kk0 + (tid & 63)] = f2bf(tile[tid & 63][co]);
        }
        return;
    }

    // ---- bilinear sampling: 4 vertices per block ----
    {
        int p = (blk - 2336) * 4 + (tid >> 6);   // b*NPTS + n
        int b = p >> 10;
        int n = p & 1023;
        int t = tid & 63;                        // 4 channels each

        float y = vertices[2 * p + 0];
        float x = vertices[2 * p + 1];
        float y0f = floorf(y), x0f = floorf(x);
        float wy1 = y - y0f, wx1 = x - x0f;
        float wy0 = 1.f - wy1, wx0 = 1.f - wx1;
        int y0 = (int)y0f, x0 = (int)x0f;

        float4 acc = make_float4(0.f, 0.f, 0.f, 0.f);
        const float4* fbase = (const float4*)features + (size_t)b * FH * FW * (FC / 4);

#define CORNER(yi, xi, wgt) {                                                  \
        int yy = (yi), xx = (xi);                                              \
        float wv = ((yy >= 0) && (yy < FH) && (xx >= 0) && (xx < FW)) ? (wgt) : 0.f; \
        int yc = yy < 0 ? 0 : (yy > FH - 1 ? FH - 1 : yy);                     \
        int xc = xx < 0 ? 0 : (xx > FW - 1 ? FW - 1 : xx);                     \
        float4 v = fbase[((size_t)yc * FW + xc) * (FC / 4) + t];               \
        acc.x += v.x * wv; acc.y += v.y * wv; acc.z += v.z * wv; acc.w += v.w * wv; }

        CORNER(y0,     x0,     wy0 * wx0);
        CORNER(y0,     x0 + 1, wy0 * wx1);
        CORNER(y0 + 1, x0,     wy1 * wx0);
        CORNER(y0 + 1, x0 + 1, wy1 * wx1);
#undef CORNER

        ushort4 o;
        o.x = f2bf(acc.x); o.y = f2bf(acc.y); o.z = f2bf(acc.z); o.w = f2bf(acc.w);
        *(ushort4*)(XpA + ((size_t)b * PADN + HALO + n) * FC + 4 * t) = o;
    }
}

// ---------------------------------------------------------------------------
// Dilated conv as MFMA GEMM, tile 128x64 (M x CO), 4 waves (2x2),
// wave tile 64x32. BK=64, TRIPLE-buffered LDS (3 x 24 KB), prefetch depth 2,
// counted vmcnt(6): tiles kt & kt+1 always in flight, ONE barrier per K-step.
// Ledger: between barrier(kt) and barrier(kt+1) waves read buf kt%3, stage
// writes buf (kt+2)%3, in-flight loads land in buf (kt+1)%3 -- all distinct;
// compute(kt-1) precedes barrier(kt), protecting buf (kt+2)%3 (== (kt-1)%3).
// Grid 512 flat, XCD decode: the 8 co-blocks of one m-panel share one XCD.
// ---------------------------------------------------------------------------
template <int CIN>
__global__ __launch_bounds__(256) void conv_mfma(
    const ushort_t* __restrict__ Xp,   // [8][1056][CIN] bf16
    const ushort_t* __restrict__ Wt,   // [512][3*CIN]  bf16
    const float* __restrict__ bias,    // [512] fp32
    ushort_t* __restrict__ Yp,         // [8][1056][512] bf16 (interior write)
    int rate)
{
    constexpr int K3 = 3 * CIN;
    constexpr int NT = K3 / 64;        // K-steps
    __shared__ short lds[3][12288];    // [buf][A(8192) | B(4096)] shorts = 72 KB

    const int tid  = threadIdx.x;
    const int wid  = tid >> 6;
    const int lane = tid & 63;
    const int wm   = wid >> 1, wn = wid & 1;

    const int h  = blockIdx.x;               // 0..511
    const int bm = (h & 7) * 8 + (h >> 6);   // 0..63  (XCD h%8 owns 8 m-panels)
    const int bn = (h >> 3) & 7;             // 0..7
    const int batch = bm >> 3;
    const int n0    = (bm & 7) * 128;
    const int co0   = bn * 64;

    const short* Xbase = (const short*)Xp + ((size_t)batch * PADN + HALO + n0) * CIN;
    const short* Wbase = (const short*)Wt + (size_t)co0 * K3;

    // ---- staging: one K-step = A[128][64] + B[64][64] bf16 tiles ----
    // 6 gload_lds(16B) per wave per tile -> vmcnt quantum = 6.
    auto stage = [&](int buf, int kt) {
        const int tap = (kt << 6) / CIN;
        const int ci0 = (kt << 6) - tap * CIN;
        const short* Ag = Xbase + (ptrdiff_t)(tap - 1) * rate * CIN + ci0;
        const short* Bg = Wbase + (kt << 6);
        short* ldsA = &lds[buf][0];
        short* ldsB = &lds[buf][8192];
#pragma unroll
        for (int it = 0; it < 4; ++it) {          // A: wave covers rows wid*32..+31
            int row  = wid * 32 + it * 8 + (lane >> 3);
            int chnk = (lane & 7) ^ (row & 7);    // inverse swizzle on src
            GLOAD16(Ag + (size_t)row * CIN + chnk * 8, ldsA + ((wid * 4 + it) << 9));
        }
#pragma unroll
        for (int it = 0; it < 2; ++it) {          // B: wave covers rows wid*16..+15
            int row  = wid * 16 + it * 8 + (lane >> 3);
            int chnk = (lane & 7) ^ (row & 7);
            GLOAD16(Bg + (size_t)row * K3 + chnk * 8, ldsB + ((wid * 2 + it) << 9));
        }
    };

    // ---- accumulators init with bias ----
    f32x16 acc[2];
    const int rowA0 = wm * 64 + (lane & 31);
    const int coB   = wn * 32 + (lane & 31);
    {
        float bv = bias[co0 + coB];
#pragma unroll
        for (int i = 0; i < 2; ++i)
#pragma unroll
            for (int r = 0; r < 16; ++r) acc[i][r] = bv;
    }

    stage(0, 0);
    stage(1, 1);

    int cur = 0;
    for (int kt = 0; kt < NT; ++kt) {
        if (kt + 1 < NT) {
            asm volatile("s_waitcnt vmcnt(6)" ::: "memory");  // tile kt landed; kt+1 in flight
        } else {
            asm volatile("s_waitcnt vmcnt(0)" ::: "memory");
        }
        __builtin_amdgcn_s_barrier();
        __builtin_amdgcn_sched_barrier(0);

        if (kt + 2 < NT) {
            int nb = cur + 2; if (nb >= 3) nb -= 3;
            stage(nb, kt + 2);                    // lands >= 2 K-steps from now
        }

        const short* As = &lds[cur][0];
        const short* Bs = &lds[cur][8192];
        __builtin_amdgcn_s_setprio(1);
#pragma unroll
        for (int ks = 0; ks < 4; ++ks) {
            int ch = ks * 2 + (lane >> 5);
            short8 av[2], bv;
#pragma unroll
            for (int i = 0; i < 2; ++i) {
                int ra = rowA0 + i * 32;
                av[i] = *(const short8*)(As + ra * 64 + ((ch ^ (ra & 7)) << 3));
            }
            bv = *(const short8*)(Bs + coB * 64 + ((ch ^ (coB & 7)) << 3));
#pragma unroll
            for (int i = 0; i < 2; ++i)
                acc[i] = __builtin_amdgcn_mfma_f32_32x32x16_bf16(
                    av[i], bv, acc[i], 0, 0, 0);
        }
        __builtin_amdgcn_s_setprio(0);
        cur += 1; if (cur >= 3) cur -= 3;
    }

    // ---- epilogue: ReLU + bf16 store into padded interior ----
    ushort_t* Yb = Yp + ((size_t)batch * PADN + HALO + n0) * HID + co0;
#pragma unroll
    for (int i = 0; i < 2; ++i) {
#pragma unroll
        for (int r = 0; r < 16; ++r) {
            int rrow = wm * 64 + i * 32 + (r & 3) + 8 * (r >> 2) + 4 * (lane >> 5);
            float v = acc[i][r];
            v = v > 0.f ? v : 0.f;
            Yb[(size_t)rrow * HID + coB] = f2bf(v);
        }
    }
}

// ---------------------------------------------------------------------------
// Offset head: out[p,:] = vertices[p,:] + h[p,:] @ w_off  (bf16 h, fp32 w)
// ---------------------------------------------------------------------------
__global__ __launch_bounds__(64) void head_kernel(
    const ushort_t* __restrict__ h, const float* __restrict__ w_off,
    const float* __restrict__ vertices, float* __restrict__ out)
{
    int p = blockIdx.x;
    int b = p >> 10, n = p & 1023;
    int t = threadIdx.x;
    const ushort_t* hr = h + ((size_t)b * PADN + HALO + n) * HID + t * 8;

    uint4 raw = *(const uint4*)hr;
    ushort_t hv[8];
    hv[0] = raw.x & 0xffff; hv[1] = raw.x >> 16;
    hv[2] = raw.y & 0xffff; hv[3] = raw.y >> 16;
    hv[4] = raw.z & 0xffff; hv[5] = raw.z >> 16;
    hv[6] = raw.w & 0xffff; hv[7] = raw.w >> 16;

    float s0 = 0.f, s1 = 0.f;
#pragma unroll
    for (int k = 0; k < 8; ++k) {
        float x = bf2f(hv[k]);
        s0 += x * w_off[(t * 8 + k) * 2 + 0];
        s1 += x * w_off[(t * 8 + k) * 2 + 1];
    }
#pragma unroll
    for (int off = 32; off >= 1; off >>= 1) {
        s0 += __shfl_down(s0, off);
        s1 += __shfl_down(s1, off);
    }
    if (t == 0) {
        out[2 * p + 0] = vertices[2 * p + 0] + s0;
        out[2 * p + 1] = vertices[2 * p + 1] + s1;
    }
}

// ---------------------------------------------------------------------------
extern "C" void kernel_launch(void* const* d_in, const int* in_sizes, int n_in,
                              void* d_out, int out_size, void* d_ws, size_t ws_size,
                              hipStream_t stream)
{
    (void)in_sizes; (void)n_in; (void)out_size; (void)ws_size;

    const float* vertices = (const float*)d_in[0];
    const float* features = (const float*)d_in[1];
    const float* w[6]  = {(const float*)d_in[2], (const float*)d_in[4],
                          (const float*)d_in[6], (const float*)d_in[8],
                          (const float*)d_in[10], (const float*)d_in[12]};
    const float* bb[6] = {(const float*)d_in[3], (const float*)d_in[5],
                          (const float*)d_in[7], (const float*)d_in[9],
                          (const float*)d_in[11], (const float*)d_in[13]};
    const float* w_off = (const float*)d_in[14];
    float* out = (float*)d_out;

    // ---- workspace layout ----
    char* p = (char*)d_ws;
    ushort_t* wt[6];
    wt[0] = (ushort_t*)p; p += (size_t)HID * (3 * FC) * 2;          // 768 KB
    for (int i = 1; i < 6; ++i) { wt[i] = (ushort_t*)p; p += (size_t)HID * (3 * HID) * 2; }
    ushort_t* XpA = (ushort_t*)p; p += (size_t)BATCH * PADN * FC  * 2;
    ushort_t* XpB = (ushort_t*)p; p += (size_t)BATCH * PADN * HID * 2;
    ushort_t* XpC = (ushort_t*)p;

    // ---- fused prep: halos + weight transpose + sampling ----
    prep_kernel<<<4384, 256, 0, stream>>>(
        vertices, features, w[0], w[1], w[2], w[3], w[4], w[5],
        wt[0], wt[1], wt[2], wt[3], wt[4], wt[5], XpA, XpB, XpC);

    // ---- conv stack (A -> B -> C -> B -> C -> B -> C) ----
    static const int rates[6] = {1, 3, 9, 9, 3, 1};
    conv_mfma<FC><<<512, 256, 0, stream>>>(XpA, wt[0], bb[0], XpB, rates[0]);
    ushort_t* src = XpB;
    ushort_t* dst = XpC;
    for (int i = 1; i < 6; ++i) {
        conv_mfma<HID><<<512, 256, 0, stream>>>(src, wt[i], bb[i], dst, rates[i]);
        ushort_t* tmp = src; src = dst; dst = tmp;
    }

    // ---- head ----
    head_kernel<<<BATCH * NPTS, 64, 0, stream>>>(src, w_off, vertices, out);
}